// Round 1
// baseline (103.607 us; speedup 1.0000x reference)
//
#include <hip/hip_runtime.h>

// GNN_51539607552576 — fully fused per-pixel GNN step.
// B=4, HID=10, IN_DIM=256, H=W=128. One thread per (b, pixel).
// All 1x1 convs => per-pixel channel dots; graph edges hand-expanded.

namespace {
constexpr int S     = 128 * 128;   // spatial size
constexpr int BATCH = 4;
constexpr int HID   = 10;
constexpr int INDIM = 256;

struct Ptrs {
  const float *xp, *xh, *xf, *p_fea, *h_fea;
  const float *Wf_comp, *bf_comp, *Wf_uatt, *bf_uatt, *Wf_uupd;
  const float *Wh_pdp_f, *Wh_pdp_x, *bh_pdp, *Wh_att, *bh_att;
  const float *Wh_cu, *bh_cu, *Wh_cl, *bh_cl;
  const float *Wh_dec_f, *Wh_dec_x, *bh_dec, *Wh_uatt, *bh_uatt, *Wh_uupd;
  const float *Wp_pdp_f, *Wp_pdp_x, *bp_pdp, *Wp_att, *bp_att;
  const float *Wp_dec_f, *Wp_dec_x, *bp_dec, *Wp_uatt, *bp_uatt, *Wp_uupd;
  float *out;
};

__device__ __forceinline__ float sigmoidf(float x) {
  return 1.0f / (1.0f + __expf(-x));
}

// att-gated fused update: out[o*S] = x[o]*(1-att) + relu(Wu·cat)*att
__device__ __forceinline__ void att_update_store(
    const float* x, const float* m,
    const float* __restrict__ Wa, float ba, const float* __restrict__ Wu,
    float* __restrict__ outp) {
  float a = ba;
#pragma unroll
  for (int c = 0; c < HID; ++c) a = fmaf(x[c], Wa[c], a);
#pragma unroll
  for (int c = 0; c < HID; ++c) a = fmaf(m[c], Wa[HID + c], a);
  a = sigmoidf(a);
#pragma unroll
  for (int o = 0; o < HID; ++o) {
    float u = 0.f;
#pragma unroll
    for (int c = 0; c < HID; ++c) u = fmaf(x[c], Wu[o * 2 * HID + c], u);
#pragma unroll
    for (int c = 0; c < HID; ++c) u = fmaf(m[c], Wu[o * 2 * HID + HID + c], u);
    u = fmaxf(u, 0.f);
    outp[(size_t)o * S] = x[o] * (1.f - a) + u * a;
  }
}

__global__ __launch_bounds__(256) void gnn_fused(Ptrs P) {
  const int tid = blockIdx.x * blockDim.x + threadIdx.x;
  const int b = tid >> 14;        // tid / S
  const int p = tid & (S - 1);    // tid % S

  // ---------------- fea projections (the 256-channel streams) ----------------
  float fh[HID] = {};                 // h_fea · Wh_pdp_f^T   [10]
  float hdec0 = 0.f, hdec1 = 0.f;     // h_fea · Wh_dec_f^T   [2]
  {
    const float* base = P.h_fea + ((size_t)b * INDIM) * S + p;
#pragma unroll 4
    for (int c = 0; c < INDIM; ++c) {
      const float v = base[(size_t)c * S];
#pragma unroll
      for (int o = 0; o < HID; ++o) fh[o] = fmaf(v, P.Wh_pdp_f[o * INDIM + c], fh[o]);
      hdec0 = fmaf(v, P.Wh_dec_f[c], hdec0);
      hdec1 = fmaf(v, P.Wh_dec_f[INDIM + c], hdec1);
    }
  }
  float fpj[HID] = {};                // p_fea · Wp_pdp_f^T   [10]
  float pdec[6] = {};                 // p_fea · Wp_dec_f^T   [6]
  {
    const float* base = P.p_fea + ((size_t)b * INDIM) * S + p;
#pragma unroll 4
    for (int c = 0; c < INDIM; ++c) {
      const float v = base[(size_t)c * S];
#pragma unroll
      for (int o = 0; o < HID; ++o) fpj[o] = fmaf(v, P.Wp_pdp_f[o * INDIM + c], fpj[o]);
#pragma unroll
      for (int n = 0; n < 6; ++n) pdec[n] = fmaf(v, P.Wp_dec_f[n * INDIM + c], pdec[n]);
    }
  }

  // ---------------- node states ----------------
  float xh0[HID], xh1[HID], xfv[HID];
#pragma unroll
  for (int c = 0; c < HID; ++c) {
    xh0[c] = P.xh[((size_t)(0 * BATCH + b) * HID + c) * S + p];
    xh1[c] = P.xh[((size_t)(1 * BATCH + b) * HID + c) * S + p];
    xfv[c] = P.xf[((size_t)b * HID + c) * S + p];
  }

  // ---------------- full graph ----------------
  {
    float a0 = P.bf_comp[0], a1 = P.bf_comp[1];
#pragma unroll
    for (int c = 0; c < HID; ++c) {
      a0 = fmaf(xh0[c], P.Wf_comp[c], a0);
      a1 = fmaf(xh1[c], P.Wf_comp[HID + c], a1);
    }
    a0 = sigmoidf(a0); a1 = sigmoidf(a1);
    float msg[HID];
#pragma unroll
    for (int c = 0; c < HID; ++c) msg[c] = a0 * xh0[c] + a1 * xh1[c];
    att_update_store(xfv, msg, P.Wf_uatt, P.bf_uatt[0], P.Wf_uupd,
                     P.out + ((size_t)(8 * BATCH + b) * HID) * S + p);
  }

  // ---------------- load xp ----------------
  float xp[6][HID];
#pragma unroll
  for (int n = 0; n < 6; ++n)
#pragma unroll
    for (int c = 0; c < HID; ++c)
      xp[n][c] = P.xp[((size_t)(n * BATCH + b) * HID + c) * S + p];

  // ---------------- half graph ----------------
  {
    float hatt0 = P.bh_att[0], hatt1 = P.bh_att[1];
#pragma unroll
    for (int c = 0; c < HID; ++c) {
      hatt0 = fmaf(xh0[c], P.Wh_att[c], hatt0);
      hatt1 = fmaf(xh1[c], P.Wh_att[HID + c], hatt1);
    }
    hatt0 = sigmoidf(hatt0); hatt1 = sigmoidf(hatt1);

    // compositions from parts
    float xphu[HID] = {}, xphl[HID] = {};
#pragma unroll
    for (int i = 0; i < 4; ++i) {
      float s = P.bh_cu[i];
#pragma unroll
      for (int c = 0; c < HID; ++c) s = fmaf(xp[i][c], P.Wh_cu[i * HID + c], s);
      s = sigmoidf(s);
#pragma unroll
      for (int c = 0; c < HID; ++c) xphu[c] = fmaf(s, xp[i][c], xphu[c]);
    }
#pragma unroll
    for (int i = 0; i < 2; ++i) {
      float s = P.bh_cl[i];
#pragma unroll
      for (int c = 0; c < HID; ++c) s = fmaf(xp[4 + i][c], P.Wh_cl[i * HID + c], s);
      s = sigmoidf(s);
#pragma unroll
      for (int c = 0; c < HID; ++c) xphl[c] = fmaf(s, xp[4 + i][c], xphl[c]);
    }

    // decomposition gates (full -> halves)
    float d0 = hdec0 + P.bh_dec[0], d1 = hdec1 + P.bh_dec[1];
#pragma unroll
    for (int c = 0; c < HID; ++c) {
      d0 = fmaf(xh0[c], P.Wh_dec_x[c], d0);
      d1 = fmaf(xh1[c], P.Wh_dec_x[HID + c], d1);
    }
    d0 = sigmoidf(d0); d1 = sigmoidf(d1);

    const float wl = hatt1 * (1.f - hatt0);  // gates h_dp[1] -> msg0 (lower->upper)
    const float wu = hatt0 * (1.f - hatt1);  // gates h_dp[0] -> msg1 (upper->lower)

    float m0[HID], m1[HID];
#pragma unroll
    for (int o = 0; o < HID; ++o) {
      const float base_o = fh[o] + P.bh_pdp[o];
      float dp0 = base_o, dp1 = base_o;
#pragma unroll
      for (int c = 0; c < HID; ++c) {
        dp0 = fmaf(xh0[c], P.Wh_pdp_x[o * HID + c], dp0);
        dp1 = fmaf(xh1[c], P.Wh_pdp_x[o * HID + c], dp1);
      }
      dp0 = fmaxf(dp0, 0.f);
      dp1 = fmaxf(dp1, 0.f);
      m0[o] = xphu[o] + dp1 * wl + d0 * xfv[o];
      m1[o] = xphl[o] + dp0 * wu + d1 * xfv[o];
    }
    att_update_store(xh0, m0, P.Wh_uatt + 0 * 2 * HID, P.bh_uatt[0],
                     P.Wh_uupd + 0 * HID * 2 * HID,
                     P.out + ((size_t)(6 * BATCH + b) * HID) * S + p);
    att_update_store(xh1, m1, P.Wh_uatt + 1 * 2 * HID, P.bh_uatt[1],
                     P.Wh_uupd + 1 * HID * 2 * HID,
                     P.out + ((size_t)(7 * BATCH + b) * HID) * S + p);
  }

  // ---------------- part graph ----------------
  {
    float patt[6];
#pragma unroll
    for (int n = 0; n < 6; ++n) {
      float s = P.bp_att[n];
#pragma unroll
      for (int c = 0; c < HID; ++c) s = fmaf(xp[n][c], P.Wp_att[n * HID + c], s);
      patt[n] = sigmoidf(s);
    }

    // g[n][o] = relu(fpj[o] + xp[n]·Wp_pdp_x[o] + bp_pdp[o]) * patt[n]
    // segment sums:  dst0,2,3 <- g1 ; dst1 <- g0+g2+g3+g4+g5 ; dst4 <- g1+g5 ; dst5 <- g1+g4
    float g1[HID], gOth[HID] = {}, g4[HID], g5[HID];
#pragma unroll
    for (int n = 0; n < 6; ++n) {
#pragma unroll
      for (int o = 0; o < HID; ++o) {
        float dp = fpj[o] + P.bp_pdp[o];
#pragma unroll
        for (int c = 0; c < HID; ++c) dp = fmaf(xp[n][c], P.Wp_pdp_x[o * HID + c], dp);
        dp = fmaxf(dp, 0.f) * patt[n];
        if (n == 1) g1[o] = dp; else gOth[o] += dp;
        if (n == 4) g4[o] = dp;
        if (n == 5) g5[o] = dp;
      }
    }

#pragma unroll
    for (int n = 0; n < 6; ++n) {
      const float onem = 1.f - patt[n];
      // decomposition gate (half -> part)
      float dg = pdec[n] + P.bp_dec[n];
#pragma unroll
      for (int c = 0; c < HID; ++c) dg = fmaf(xp[n][c], P.Wp_dec_x[n * HID + c], dg);
      dg = sigmoidf(dg);

      float m[HID];
#pragma unroll
      for (int o = 0; o < HID; ++o) {
        float sum;
        if (n == 0 || n == 2 || n == 3) sum = g1[o];
        else if (n == 1)                sum = gOth[o];
        else if (n == 4)                sum = g1[o] + g5[o];
        else                            sum = g1[o] + g4[o];
        const float xh_src = (n < 4) ? xh0[o] : xh1[o];   // HALF_IDX
        m[o] = onem * sum + dg * xh_src;
      }
      att_update_store(xp[n], m, P.Wp_uatt + n * 2 * HID, P.bp_uatt[n],
                       P.Wp_uupd + n * HID * 2 * HID,
                       P.out + ((size_t)(n * BATCH + b) * HID) * S + p);
    }
  }
}

}  // namespace

extern "C" void kernel_launch(void* const* d_in, const int* in_sizes, int n_in,
                              void* d_out, int out_size, void* d_ws, size_t ws_size,
                              hipStream_t stream) {
  Ptrs P;
  P.xp       = (const float*)d_in[0];
  P.xh       = (const float*)d_in[1];
  P.xf       = (const float*)d_in[2];
  // d_in[3] = bg_node (unused by reference)
  P.p_fea    = (const float*)d_in[4];
  P.h_fea    = (const float*)d_in[5];
  // d_in[6] = f_fea (unused by reference)
  P.Wf_comp  = (const float*)d_in[7];
  P.bf_comp  = (const float*)d_in[8];
  P.Wf_uatt  = (const float*)d_in[9];
  P.bf_uatt  = (const float*)d_in[10];
  P.Wf_uupd  = (const float*)d_in[11];
  P.Wh_pdp_f = (const float*)d_in[12];
  P.Wh_pdp_x = (const float*)d_in[13];
  P.bh_pdp   = (const float*)d_in[14];
  P.Wh_att   = (const float*)d_in[15];
  P.bh_att   = (const float*)d_in[16];
  P.Wh_cu    = (const float*)d_in[17];
  P.bh_cu    = (const float*)d_in[18];
  P.Wh_cl    = (const float*)d_in[19];
  P.bh_cl    = (const float*)d_in[20];
  P.Wh_dec_f = (const float*)d_in[21];
  P.Wh_dec_x = (const float*)d_in[22];
  P.bh_dec   = (const float*)d_in[23];
  P.Wh_uatt  = (const float*)d_in[24];
  P.bh_uatt  = (const float*)d_in[25];
  P.Wh_uupd  = (const float*)d_in[26];
  P.Wp_pdp_f = (const float*)d_in[27];
  P.Wp_pdp_x = (const float*)d_in[28];
  P.bp_pdp   = (const float*)d_in[29];
  P.Wp_att   = (const float*)d_in[30];
  P.bp_att   = (const float*)d_in[31];
  P.Wp_dec_f = (const float*)d_in[32];
  P.Wp_dec_x = (const float*)d_in[33];
  P.bp_dec   = (const float*)d_in[34];
  P.Wp_uatt  = (const float*)d_in[35];
  P.bp_uatt  = (const float*)d_in[36];
  P.Wp_uupd  = (const float*)d_in[37];
  P.out      = (float*)d_out;

  const int total = BATCH * S;              // 65536 threads, 1 per (b, pixel)
  gnn_fused<<<dim3(total / 256), dim3(256), 0, stream>>>(P);
}

// Round 2
// 85.098 us; speedup vs baseline: 1.2175x; 1.2175x over previous
//
#include <hip/hip_runtime.h>

// GNN_51539607552576 — two-phase fused GNN step.
// Phase 1: fea projections [65536 x 256] x [256 x 28] -> d_ws (SoA), parallelized
//          64 px x 4 channel-slices per block for occupancy/latency hiding.
// Phase 2: per-pixel graph math (1 thread per (b,pixel)), reads projections.

namespace {
constexpr int S     = 128 * 128;   // spatial size per batch
constexpr int BATCH = 4;
constexpr int HID   = 10;
constexpr int INDIM = 256;
constexpr int NPIX  = BATCH * S;   // 65536

struct Ptrs {
  const float *xp, *xh, *xf, *p_fea, *h_fea;
  const float *Wf_comp, *bf_comp, *Wf_uatt, *bf_uatt, *Wf_uupd;
  const float *Wh_pdp_f, *Wh_pdp_x, *bh_pdp, *Wh_att, *bh_att;
  const float *Wh_cu, *bh_cu, *Wh_cl, *bh_cl;
  const float *Wh_dec_f, *Wh_dec_x, *bh_dec, *Wh_uatt, *bh_uatt, *Wh_uupd;
  const float *Wp_pdp_f, *Wp_pdp_x, *bp_pdp, *Wp_att, *bp_att;
  const float *Wp_dec_f, *Wp_dec_x, *bp_dec, *Wp_uatt, *bp_uatt, *Wp_uupd;
  float *out;
  float *ws;
};

__device__ __forceinline__ float sigmoidf(float x) {
  return 1.0f / (1.0f + __expf(-x));
}

// ============================ Phase 1: projections ============================
// ws rows: 0..9 fh (h_fea·Wh_pdp_f^T), 10..11 hdec (h_fea·Wh_dec_f^T),
//          12..21 fpj (p_fea·Wp_pdp_f^T), 22..27 pdec (p_fea·Wp_dec_f^T)

template <int NO>  // NO = 12 (h stream) or 16 (p stream)
__device__ __forceinline__ void proj_impl(
    float (*lds)[64][17],
    const float* __restrict__ fea,
    const float* __restrict__ Wa,   // [10][INDIM]
    const float* __restrict__ Wb,   // [NO-10][INDIM]
    float* __restrict__ ws, int obase) {
  const int t  = threadIdx.x;
  const int px = t & 63;
  const int sl = __builtin_amdgcn_readfirstlane(t >> 6);  // wave-uniform slice
  const int gp = blockIdx.x * 64 + px;                    // global pixel id
  const int b  = gp >> 14;
  const int p  = gp & (S - 1);

  float acc[NO];
#pragma unroll
  for (int o = 0; o < NO; ++o) acc[o] = 0.f;

  const float* base = fea + ((size_t)(b * INDIM + sl * 64)) * S + p;
#pragma unroll 8
  for (int cl = 0; cl < 64; ++cl) {
    const int c   = sl * 64 + cl;      // wave-uniform channel index
    const float v = base[(size_t)cl * S];
#pragma unroll
    for (int o = 0; o < 10; ++o) acc[o] = fmaf(v, Wa[o * INDIM + c], acc[o]);
#pragma unroll
    for (int o = 10; o < NO; ++o) acc[o] = fmaf(v, Wb[(o - 10) * INDIM + c], acc[o]);
  }

#pragma unroll
  for (int o = 0; o < NO; ++o) lds[sl][px][o] = acc[o];
  __syncthreads();

  // reduce 4 slices; 256 threads = 64 px x 4 output-groups
  constexpr int K = NO / 4;
  const int og = t >> 6;
#pragma unroll
  for (int k = 0; k < K; ++k) {
    const int o = og * K + k;
    const float s = lds[0][px][o] + lds[1][px][o] + lds[2][px][o] + lds[3][px][o];
    ws[(size_t)(obase + o) * NPIX + gp] = s;
  }
}

__global__ __launch_bounds__(256) void proj_kernel(Ptrs P) {
  __shared__ float lds[4][64][17];   // pad 17: odd stride -> conflict-free
  if (blockIdx.y == 0) {
    proj_impl<12>(lds, P.h_fea, P.Wh_pdp_f, P.Wh_dec_f, P.ws, 0);
  } else {
    proj_impl<16>(lds, P.p_fea, P.Wp_pdp_f, P.Wp_dec_f, P.ws, 12);
  }
}

// ============================ Phase 2: graph math ============================

__device__ __forceinline__ void att_update_store(
    const float* x, const float* m,
    const float* __restrict__ Wa, float ba, const float* __restrict__ Wu,
    float* __restrict__ outp) {
  float a = ba;
#pragma unroll
  for (int c = 0; c < HID; ++c) a = fmaf(x[c], Wa[c], a);
#pragma unroll
  for (int c = 0; c < HID; ++c) a = fmaf(m[c], Wa[HID + c], a);
  a = sigmoidf(a);
#pragma unroll
  for (int o = 0; o < HID; ++o) {
    float u = 0.f;
#pragma unroll
    for (int c = 0; c < HID; ++c) u = fmaf(x[c], Wu[o * 2 * HID + c], u);
#pragma unroll
    for (int c = 0; c < HID; ++c) u = fmaf(m[c], Wu[o * 2 * HID + HID + c], u);
    u = fmaxf(u, 0.f);
    outp[(size_t)o * S] = x[o] * (1.f - a) + u * a;
  }
}

__global__ __launch_bounds__(256) void gnn_main(Ptrs P) {
  const int tid = blockIdx.x * blockDim.x + threadIdx.x;
  const int b = tid >> 14;
  const int p = tid & (S - 1);

  // ---------------- projections from ws ----------------
  float fh[HID], fpj[HID], pdec[6];
#pragma unroll
  for (int o = 0; o < HID; ++o) fh[o] = P.ws[(size_t)o * NPIX + tid];
  const float hdec0 = P.ws[(size_t)10 * NPIX + tid];
  const float hdec1 = P.ws[(size_t)11 * NPIX + tid];
#pragma unroll
  for (int o = 0; o < HID; ++o) fpj[o] = P.ws[(size_t)(12 + o) * NPIX + tid];
#pragma unroll
  for (int n = 0; n < 6; ++n) pdec[n] = P.ws[(size_t)(22 + n) * NPIX + tid];

  // ---------------- node states ----------------
  float xh0[HID], xh1[HID], xfv[HID];
#pragma unroll
  for (int c = 0; c < HID; ++c) {
    xh0[c] = P.xh[((size_t)(0 * BATCH + b) * HID + c) * S + p];
    xh1[c] = P.xh[((size_t)(1 * BATCH + b) * HID + c) * S + p];
    xfv[c] = P.xf[((size_t)b * HID + c) * S + p];
  }

  // ---------------- full graph ----------------
  {
    float a0 = P.bf_comp[0], a1 = P.bf_comp[1];
#pragma unroll
    for (int c = 0; c < HID; ++c) {
      a0 = fmaf(xh0[c], P.Wf_comp[c], a0);
      a1 = fmaf(xh1[c], P.Wf_comp[HID + c], a1);
    }
    a0 = sigmoidf(a0); a1 = sigmoidf(a1);
    float msg[HID];
#pragma unroll
    for (int c = 0; c < HID; ++c) msg[c] = a0 * xh0[c] + a1 * xh1[c];
    att_update_store(xfv, msg, P.Wf_uatt, P.bf_uatt[0], P.Wf_uupd,
                     P.out + ((size_t)(8 * BATCH + b) * HID) * S + p);
  }

  // ---------------- load xp ----------------
  float xp[6][HID];
#pragma unroll
  for (int n = 0; n < 6; ++n)
#pragma unroll
    for (int c = 0; c < HID; ++c)
      xp[n][c] = P.xp[((size_t)(n * BATCH + b) * HID + c) * S + p];

  // ---------------- half graph ----------------
  {
    float hatt0 = P.bh_att[0], hatt1 = P.bh_att[1];
#pragma unroll
    for (int c = 0; c < HID; ++c) {
      hatt0 = fmaf(xh0[c], P.Wh_att[c], hatt0);
      hatt1 = fmaf(xh1[c], P.Wh_att[HID + c], hatt1);
    }
    hatt0 = sigmoidf(hatt0); hatt1 = sigmoidf(hatt1);

    float xphu[HID] = {}, xphl[HID] = {};
#pragma unroll
    for (int i = 0; i < 4; ++i) {
      float s = P.bh_cu[i];
#pragma unroll
      for (int c = 0; c < HID; ++c) s = fmaf(xp[i][c], P.Wh_cu[i * HID + c], s);
      s = sigmoidf(s);
#pragma unroll
      for (int c = 0; c < HID; ++c) xphu[c] = fmaf(s, xp[i][c], xphu[c]);
    }
#pragma unroll
    for (int i = 0; i < 2; ++i) {
      float s = P.bh_cl[i];
#pragma unroll
      for (int c = 0; c < HID; ++c) s = fmaf(xp[4 + i][c], P.Wh_cl[i * HID + c], s);
      s = sigmoidf(s);
#pragma unroll
      for (int c = 0; c < HID; ++c) xphl[c] = fmaf(s, xp[4 + i][c], xphl[c]);
    }

    float d0 = hdec0 + P.bh_dec[0], d1 = hdec1 + P.bh_dec[1];
#pragma unroll
    for (int c = 0; c < HID; ++c) {
      d0 = fmaf(xh0[c], P.Wh_dec_x[c], d0);
      d1 = fmaf(xh1[c], P.Wh_dec_x[HID + c], d1);
    }
    d0 = sigmoidf(d0); d1 = sigmoidf(d1);

    const float wl = hatt1 * (1.f - hatt0);
    const float wu = hatt0 * (1.f - hatt1);

    float m0[HID], m1[HID];
#pragma unroll
    for (int o = 0; o < HID; ++o) {
      const float base_o = fh[o] + P.bh_pdp[o];
      float dp0 = base_o, dp1 = base_o;
#pragma unroll
      for (int c = 0; c < HID; ++c) {
        dp0 = fmaf(xh0[c], P.Wh_pdp_x[o * HID + c], dp0);
        dp1 = fmaf(xh1[c], P.Wh_pdp_x[o * HID + c], dp1);
      }
      dp0 = fmaxf(dp0, 0.f);
      dp1 = fmaxf(dp1, 0.f);
      m0[o] = xphu[o] + dp1 * wl + d0 * xfv[o];
      m1[o] = xphl[o] + dp0 * wu + d1 * xfv[o];
    }
    att_update_store(xh0, m0, P.Wh_uatt + 0 * 2 * HID, P.bh_uatt[0],
                     P.Wh_uupd + 0 * HID * 2 * HID,
                     P.out + ((size_t)(6 * BATCH + b) * HID) * S + p);
    att_update_store(xh1, m1, P.Wh_uatt + 1 * 2 * HID, P.bh_uatt[1],
                     P.Wh_uupd + 1 * HID * 2 * HID,
                     P.out + ((size_t)(7 * BATCH + b) * HID) * S + p);
  }

  // ---------------- part graph ----------------
  {
    float patt[6];
#pragma unroll
    for (int n = 0; n < 6; ++n) {
      float s = P.bp_att[n];
#pragma unroll
      for (int c = 0; c < HID; ++c) s = fmaf(xp[n][c], P.Wp_att[n * HID + c], s);
      patt[n] = sigmoidf(s);
    }

    float g1[HID], gOth[HID] = {}, g4[HID], g5[HID];
#pragma unroll
    for (int n = 0; n < 6; ++n) {
#pragma unroll
      for (int o = 0; o < HID; ++o) {
        float dp = fpj[o] + P.bp_pdp[o];
#pragma unroll
        for (int c = 0; c < HID; ++c) dp = fmaf(xp[n][c], P.Wp_pdp_x[o * HID + c], dp);
        dp = fmaxf(dp, 0.f) * patt[n];
        if (n == 1) g1[o] = dp; else gOth[o] += dp;
        if (n == 4) g4[o] = dp;
        if (n == 5) g5[o] = dp;
      }
    }

#pragma unroll
    for (int n = 0; n < 6; ++n) {
      const float onem = 1.f - patt[n];
      float dg = pdec[n] + P.bp_dec[n];
#pragma unroll
      for (int c = 0; c < HID; ++c) dg = fmaf(xp[n][c], P.Wp_dec_x[n * HID + c], dg);
      dg = sigmoidf(dg);

      float m[HID];
#pragma unroll
      for (int o = 0; o < HID; ++o) {
        float sum;
        if (n == 0 || n == 2 || n == 3) sum = g1[o];
        else if (n == 1)                sum = gOth[o];
        else if (n == 4)                sum = g1[o] + g5[o];
        else                            sum = g1[o] + g4[o];
        const float xh_src = (n < 4) ? xh0[o] : xh1[o];
        m[o] = onem * sum + dg * xh_src;
      }
      att_update_store(xp[n], m, P.Wp_uatt + n * 2 * HID, P.bp_uatt[n],
                       P.Wp_uupd + n * HID * 2 * HID,
                       P.out + ((size_t)(n * BATCH + b) * HID) * S + p);
    }
  }
}

}  // namespace

extern "C" void kernel_launch(void* const* d_in, const int* in_sizes, int n_in,
                              void* d_out, int out_size, void* d_ws, size_t ws_size,
                              hipStream_t stream) {
  Ptrs P;
  P.xp       = (const float*)d_in[0];
  P.xh       = (const float*)d_in[1];
  P.xf       = (const float*)d_in[2];
  // d_in[3] = bg_node (unused)
  P.p_fea    = (const float*)d_in[4];
  P.h_fea    = (const float*)d_in[5];
  // d_in[6] = f_fea (unused)
  P.Wf_comp  = (const float*)d_in[7];
  P.bf_comp  = (const float*)d_in[8];
  P.Wf_uatt  = (const float*)d_in[9];
  P.bf_uatt  = (const float*)d_in[10];
  P.Wf_uupd  = (const float*)d_in[11];
  P.Wh_pdp_f = (const float*)d_in[12];
  P.Wh_pdp_x = (const float*)d_in[13];
  P.bh_pdp   = (const float*)d_in[14];
  P.Wh_att   = (const float*)d_in[15];
  P.bh_att   = (const float*)d_in[16];
  P.Wh_cu    = (const float*)d_in[17];
  P.bh_cu    = (const float*)d_in[18];
  P.Wh_cl    = (const float*)d_in[19];
  P.bh_cl    = (const float*)d_in[20];
  P.Wh_dec_f = (const float*)d_in[21];
  P.Wh_dec_x = (const float*)d_in[22];
  P.bh_dec   = (const float*)d_in[23];
  P.Wh_uatt  = (const float*)d_in[24];
  P.bh_uatt  = (const float*)d_in[25];
  P.Wh_uupd  = (const float*)d_in[26];
  P.Wp_pdp_f = (const float*)d_in[27];
  P.Wp_pdp_x = (const float*)d_in[28];
  P.bp_pdp   = (const float*)d_in[29];
  P.Wp_att   = (const float*)d_in[30];
  P.bp_att   = (const float*)d_in[31];
  P.Wp_dec_f = (const float*)d_in[32];
  P.Wp_dec_x = (const float*)d_in[33];
  P.bp_dec   = (const float*)d_in[34];
  P.Wp_uatt  = (const float*)d_in[35];
  P.bp_uatt  = (const float*)d_in[36];
  P.Wp_uupd  = (const float*)d_in[37];
  P.out      = (float*)d_out;
  P.ws       = (float*)d_ws;   // needs 28 * 65536 * 4 = 7.34 MB

  // Phase 1: 2048 blocks (1024 pixel-blocks x 2 streams), 256 thr each
  proj_kernel<<<dim3(NPIX / 64, 2), dim3(256), 0, stream>>>(P);
  // Phase 2: 1 thread per (b, pixel)
  gnn_main<<<dim3(NPIX / 256), dim3(256), 0, stream>>>(P);
}

// Round 3
// 76.818 us; speedup vs baseline: 1.3487x; 1.1078x over previous
//
#include <hip/hip_runtime.h>

// GNN_51539607552576 — two-phase fused GNN step, round 3.
// Phase 1 (proj): fea projections [65536 x 256] x [256 x 28] -> d_ws (SoA).
//   float2 pixel-vectorized loads (512 B/wave), 4 channel-slices, full unroll
//   -> deep vmem pipeline. 1024 blocks = 4/CU.
// Phase 2 (gnn_main): per-pixel graph math, all loads hoisted, __restrict__.

namespace {
constexpr int S     = 128 * 128;   // spatial size per batch
constexpr int BATCH = 4;
constexpr int HID   = 10;
constexpr int INDIM = 256;
constexpr int NPIX  = BATCH * S;   // 65536

struct Ptrs {
  const float* __restrict__ xp;
  const float* __restrict__ xh;
  const float* __restrict__ xf;
  const float* __restrict__ p_fea;
  const float* __restrict__ h_fea;
  const float* __restrict__ Wf_comp;  const float* __restrict__ bf_comp;
  const float* __restrict__ Wf_uatt;  const float* __restrict__ bf_uatt;
  const float* __restrict__ Wf_uupd;
  const float* __restrict__ Wh_pdp_f; const float* __restrict__ Wh_pdp_x;
  const float* __restrict__ bh_pdp;
  const float* __restrict__ Wh_att;   const float* __restrict__ bh_att;
  const float* __restrict__ Wh_cu;    const float* __restrict__ bh_cu;
  const float* __restrict__ Wh_cl;    const float* __restrict__ bh_cl;
  const float* __restrict__ Wh_dec_f; const float* __restrict__ Wh_dec_x;
  const float* __restrict__ bh_dec;
  const float* __restrict__ Wh_uatt;  const float* __restrict__ bh_uatt;
  const float* __restrict__ Wh_uupd;
  const float* __restrict__ Wp_pdp_f; const float* __restrict__ Wp_pdp_x;
  const float* __restrict__ bp_pdp;
  const float* __restrict__ Wp_att;   const float* __restrict__ bp_att;
  const float* __restrict__ Wp_dec_f; const float* __restrict__ Wp_dec_x;
  const float* __restrict__ bp_dec;
  const float* __restrict__ Wp_uatt;  const float* __restrict__ bp_uatt;
  const float* __restrict__ Wp_uupd;
  float* __restrict__ out;
  float* __restrict__ ws;
};

__device__ __forceinline__ float sigmoidf(float x) {
  return 1.0f / (1.0f + __expf(-x));
}

// ============================ Phase 1: projections ============================
// ws rows: 0..9 fh, 10..11 hdec, 12..21 fpj, 22..27 pdec.  Column = pixel id.
// Block: 256 thr = 64 px-groups (x2 px float2) x 4 slices (64 ch each).

constexpr int LROW = 33;   // LDS row stride in floats (odd -> conflict-free)

template <int NO>  // 12 (h stream) or 16 (p stream)
__device__ __forceinline__ void proj_impl(
    float* lds,                          // [4*64][LROW]
    const float* __restrict__ fea,
    const float* __restrict__ Wa,        // [10][INDIM]
    const float* __restrict__ Wb,        // [NO-10][INDIM]
    float* __restrict__ ws, int obase) {
  const int t   = threadIdx.x;
  const int pxg = t & 63;
  const int sl  = __builtin_amdgcn_readfirstlane(t >> 6);  // wave-uniform slice
  const int pb  = blockIdx.x * 128;        // block pixel base (uniform)
  const int b   = pb >> 14;                // batch (uniform; 128 | 16384)
  const int p0  = pb & (S - 1);            // pixel offset in batch (uniform)

  float2 acc[NO];
#pragma unroll
  for (int o = 0; o < NO; ++o) { acc[o].x = 0.f; acc[o].y = 0.f; }

  // float2 base: element index (b*INDIM + sl*64)*S + p0, halved, + pxg
  const float2* __restrict__ base =
      (const float2*)fea + (((size_t)(b * INDIM + sl * 64) * S + p0) >> 1) + pxg;
#pragma unroll
  for (int cl = 0; cl < 64; ++cl) {
    const int c = sl * 64 + cl;                    // wave-uniform -> s_load W
    const float2 v = base[(size_t)cl * (S / 2)];
#pragma unroll
    for (int o = 0; o < 10; ++o) {
      const float w = Wa[o * INDIM + c];
      acc[o].x = fmaf(v.x, w, acc[o].x);
      acc[o].y = fmaf(v.y, w, acc[o].y);
    }
#pragma unroll
    for (int o = 10; o < NO; ++o) {
      const float w = Wb[(o - 10) * INDIM + c];
      acc[o].x = fmaf(v.x, w, acc[o].x);
      acc[o].y = fmaf(v.y, w, acc[o].y);
    }
  }

  // stage: row (sl*64+pxg), 2*NO consecutive floats
  float* row = lds + (sl * 64 + pxg) * LROW;
#pragma unroll
  for (int o = 0; o < NO; ++o) {
    row[2 * o]     = acc[o].x;
    row[2 * o + 1] = acc[o].y;
  }
  __syncthreads();

  // reduce 4 slices: 256 thr = 64 pxg x 4 output-groups of K outputs
  constexpr int K = NO / 4;
  const int og = t >> 6;
#pragma unroll
  for (int k = 0; k < K; ++k) {
    const int o = og * K + k;
    float sx = 0.f, sy = 0.f;
#pragma unroll
    for (int s2 = 0; s2 < 4; ++s2) {
      const float* r2 = lds + (s2 * 64 + pxg) * LROW;
      sx += r2[2 * o];
      sy += r2[2 * o + 1];
    }
    float2 res; res.x = sx; res.y = sy;
    *(float2*)(ws + (size_t)(obase + o) * NPIX + pb + pxg * 2) = res;
  }
}

__global__ __launch_bounds__(256) void proj_kernel(Ptrs P) {
  __shared__ float lds[4 * 64 * LROW];   // 33.8 KB
  if (blockIdx.y == 0) {
    proj_impl<12>(lds, P.h_fea, P.Wh_pdp_f, P.Wh_dec_f, P.ws, 0);
  } else {
    proj_impl<16>(lds, P.p_fea, P.Wp_pdp_f, P.Wp_dec_f, P.ws, 12);
  }
}

// ============================ Phase 2: graph math ============================

__device__ __forceinline__ void att_update_store(
    const float* x, const float* m,
    const float* __restrict__ Wa, float ba, const float* __restrict__ Wu,
    float* __restrict__ outp) {
  float a = ba;
#pragma unroll
  for (int c = 0; c < HID; ++c) a = fmaf(x[c], Wa[c], a);
#pragma unroll
  for (int c = 0; c < HID; ++c) a = fmaf(m[c], Wa[HID + c], a);
  a = sigmoidf(a);
#pragma unroll
  for (int o = 0; o < HID; ++o) {
    float u = 0.f;
#pragma unroll
    for (int c = 0; c < HID; ++c) u = fmaf(x[c], Wu[o * 2 * HID + c], u);
#pragma unroll
    for (int c = 0; c < HID; ++c) u = fmaf(m[c], Wu[o * 2 * HID + HID + c], u);
    u = fmaxf(u, 0.f);
    outp[(size_t)o * S] = x[o] * (1.f - a) + u * a;
  }
}

__global__ __launch_bounds__(256) void gnn_main(Ptrs P) {
  const int tid = blockIdx.x * blockDim.x + threadIdx.x;
  const int b = tid >> 14;
  const int p = tid & (S - 1);

  // ---------------- hoist ALL global loads (independent; deep vmem pipe) ----
  float fh[HID], fpj[HID], pdec[6];
#pragma unroll
  for (int o = 0; o < HID; ++o) fh[o] = P.ws[(size_t)o * NPIX + tid];
  const float hdec0 = P.ws[(size_t)10 * NPIX + tid];
  const float hdec1 = P.ws[(size_t)11 * NPIX + tid];
#pragma unroll
  for (int o = 0; o < HID; ++o) fpj[o] = P.ws[(size_t)(12 + o) * NPIX + tid];
#pragma unroll
  for (int n = 0; n < 6; ++n) pdec[n] = P.ws[(size_t)(22 + n) * NPIX + tid];

  float xh0[HID], xh1[HID], xfv[HID];
#pragma unroll
  for (int c = 0; c < HID; ++c) {
    xh0[c] = P.xh[((size_t)(0 * BATCH + b) * HID + c) * S + p];
    xh1[c] = P.xh[((size_t)(1 * BATCH + b) * HID + c) * S + p];
    xfv[c] = P.xf[((size_t)b * HID + c) * S + p];
  }
  float xp[6][HID];
#pragma unroll
  for (int n = 0; n < 6; ++n)
#pragma unroll
    for (int c = 0; c < HID; ++c)
      xp[n][c] = P.xp[((size_t)(n * BATCH + b) * HID + c) * S + p];

  // ---------------- full graph ----------------
  {
    float a0 = P.bf_comp[0], a1 = P.bf_comp[1];
#pragma unroll
    for (int c = 0; c < HID; ++c) {
      a0 = fmaf(xh0[c], P.Wf_comp[c], a0);
      a1 = fmaf(xh1[c], P.Wf_comp[HID + c], a1);
    }
    a0 = sigmoidf(a0); a1 = sigmoidf(a1);
    float msg[HID];
#pragma unroll
    for (int c = 0; c < HID; ++c) msg[c] = a0 * xh0[c] + a1 * xh1[c];
    att_update_store(xfv, msg, P.Wf_uatt, P.bf_uatt[0], P.Wf_uupd,
                     P.out + ((size_t)(8 * BATCH + b) * HID) * S + p);
  }

  // ---------------- half graph ----------------
  {
    float hatt0 = P.bh_att[0], hatt1 = P.bh_att[1];
#pragma unroll
    for (int c = 0; c < HID; ++c) {
      hatt0 = fmaf(xh0[c], P.Wh_att[c], hatt0);
      hatt1 = fmaf(xh1[c], P.Wh_att[HID + c], hatt1);
    }
    hatt0 = sigmoidf(hatt0); hatt1 = sigmoidf(hatt1);

    float xphu[HID] = {}, xphl[HID] = {};
#pragma unroll
    for (int i = 0; i < 4; ++i) {
      float s = P.bh_cu[i];
#pragma unroll
      for (int c = 0; c < HID; ++c) s = fmaf(xp[i][c], P.Wh_cu[i * HID + c], s);
      s = sigmoidf(s);
#pragma unroll
      for (int c = 0; c < HID; ++c) xphu[c] = fmaf(s, xp[i][c], xphu[c]);
    }
#pragma unroll
    for (int i = 0; i < 2; ++i) {
      float s = P.bh_cl[i];
#pragma unroll
      for (int c = 0; c < HID; ++c) s = fmaf(xp[4 + i][c], P.Wh_cl[i * HID + c], s);
      s = sigmoidf(s);
#pragma unroll
      for (int c = 0; c < HID; ++c) xphl[c] = fmaf(s, xp[4 + i][c], xphl[c]);
    }

    float d0 = hdec0 + P.bh_dec[0], d1 = hdec1 + P.bh_dec[1];
#pragma unroll
    for (int c = 0; c < HID; ++c) {
      d0 = fmaf(xh0[c], P.Wh_dec_x[c], d0);
      d1 = fmaf(xh1[c], P.Wh_dec_x[HID + c], d1);
    }
    d0 = sigmoidf(d0); d1 = sigmoidf(d1);

    const float wl = hatt1 * (1.f - hatt0);
    const float wu = hatt0 * (1.f - hatt1);

    float m0[HID], m1[HID];
#pragma unroll
    for (int o = 0; o < HID; ++o) {
      const float base_o = fh[o] + P.bh_pdp[o];
      float dp0 = base_o, dp1 = base_o;
#pragma unroll
      for (int c = 0; c < HID; ++c) {
        dp0 = fmaf(xh0[c], P.Wh_pdp_x[o * HID + c], dp0);
        dp1 = fmaf(xh1[c], P.Wh_pdp_x[o * HID + c], dp1);
      }
      dp0 = fmaxf(dp0, 0.f);
      dp1 = fmaxf(dp1, 0.f);
      m0[o] = xphu[o] + dp1 * wl + d0 * xfv[o];
      m1[o] = xphl[o] + dp0 * wu + d1 * xfv[o];
    }
    att_update_store(xh0, m0, P.Wh_uatt + 0 * 2 * HID, P.bh_uatt[0],
                     P.Wh_uupd + 0 * HID * 2 * HID,
                     P.out + ((size_t)(6 * BATCH + b) * HID) * S + p);
    att_update_store(xh1, m1, P.Wh_uatt + 1 * 2 * HID, P.bh_uatt[1],
                     P.Wh_uupd + 1 * HID * 2 * HID,
                     P.out + ((size_t)(7 * BATCH + b) * HID) * S + p);
  }

  // ---------------- part graph ----------------
  {
    float patt[6];
#pragma unroll
    for (int n = 0; n < 6; ++n) {
      float s = P.bp_att[n];
#pragma unroll
      for (int c = 0; c < HID; ++c) s = fmaf(xp[n][c], P.Wp_att[n * HID + c], s);
      patt[n] = sigmoidf(s);
    }

    float g1[HID], gOth[HID] = {}, g4[HID], g5[HID];
#pragma unroll
    for (int n = 0; n < 6; ++n) {
#pragma unroll
      for (int o = 0; o < HID; ++o) {
        float dp = fpj[o] + P.bp_pdp[o];
#pragma unroll
        for (int c = 0; c < HID; ++c) dp = fmaf(xp[n][c], P.Wp_pdp_x[o * HID + c], dp);
        dp = fmaxf(dp, 0.f) * patt[n];
        if (n == 1) g1[o] = dp; else gOth[o] += dp;
        if (n == 4) g4[o] = dp;
        if (n == 5) g5[o] = dp;
      }
    }

#pragma unroll
    for (int n = 0; n < 6; ++n) {
      const float onem = 1.f - patt[n];
      float dg = pdec[n] + P.bp_dec[n];
#pragma unroll
      for (int c = 0; c < HID; ++c) dg = fmaf(xp[n][c], P.Wp_dec_x[n * HID + c], dg);
      dg = sigmoidf(dg);

      float m[HID];
#pragma unroll
      for (int o = 0; o < HID; ++o) {
        float sum;
        if (n == 0 || n == 2 || n == 3) sum = g1[o];
        else if (n == 1)                sum = gOth[o];
        else if (n == 4)                sum = g1[o] + g5[o];
        else                            sum = g1[o] + g4[o];
        const float xh_src = (n < 4) ? xh0[o] : xh1[o];
        m[o] = onem * sum + dg * xh_src;
      }
      att_update_store(xp[n], m, P.Wp_uatt + n * 2 * HID, P.bp_uatt[n],
                       P.Wp_uupd + n * HID * 2 * HID,
                       P.out + ((size_t)(n * BATCH + b) * HID) * S + p);
    }
  }
}

}  // namespace

extern "C" void kernel_launch(void* const* d_in, const int* in_sizes, int n_in,
                              void* d_out, int out_size, void* d_ws, size_t ws_size,
                              hipStream_t stream) {
  Ptrs P;
  P.xp       = (const float*)d_in[0];
  P.xh       = (const float*)d_in[1];
  P.xf       = (const float*)d_in[2];
  // d_in[3] = bg_node (unused)
  P.p_fea    = (const float*)d_in[4];
  P.h_fea    = (const float*)d_in[5];
  // d_in[6] = f_fea (unused)
  P.Wf_comp  = (const float*)d_in[7];
  P.bf_comp  = (const float*)d_in[8];
  P.Wf_uatt  = (const float*)d_in[9];
  P.bf_uatt  = (const float*)d_in[10];
  P.Wf_uupd  = (const float*)d_in[11];
  P.Wh_pdp_f = (const float*)d_in[12];
  P.Wh_pdp_x = (const float*)d_in[13];
  P.bh_pdp   = (const float*)d_in[14];
  P.Wh_att   = (const float*)d_in[15];
  P.bh_att   = (const float*)d_in[16];
  P.Wh_cu    = (const float*)d_in[17];
  P.bh_cu    = (const float*)d_in[18];
  P.Wh_cl    = (const float*)d_in[19];
  P.bh_cl    = (const float*)d_in[20];
  P.Wh_dec_f = (const float*)d_in[21];
  P.Wh_dec_x = (const float*)d_in[22];
  P.bh_dec   = (const float*)d_in[23];
  P.Wh_uatt  = (const float*)d_in[24];
  P.bh_uatt  = (const float*)d_in[25];
  P.Wh_uupd  = (const float*)d_in[26];
  P.Wp_pdp_f = (const float*)d_in[27];
  P.Wp_pdp_x = (const float*)d_in[28];
  P.bp_pdp   = (const float*)d_in[29];
  P.Wp_att   = (const float*)d_in[30];
  P.bp_att   = (const float*)d_in[31];
  P.Wp_dec_f = (const float*)d_in[32];
  P.Wp_dec_x = (const float*)d_in[33];
  P.bp_dec   = (const float*)d_in[34];
  P.Wp_uatt  = (const float*)d_in[35];
  P.bp_uatt  = (const float*)d_in[36];
  P.Wp_uupd  = (const float*)d_in[37];
  P.out      = (float*)d_out;
  P.ws       = (float*)d_ws;   // 28 * 65536 * 4 = 7.34 MB

  // Phase 1: 512 pixel-blocks x 2 streams, 256 thr each (4 blocks/CU)
  proj_kernel<<<dim3(NPIX / 128, 2), dim3(256), 0, stream>>>(P);
  // Phase 2: 1 thread per (b, pixel)
  gnn_main<<<dim3(NPIX / 256), dim3(256), 0, stream>>>(P);
}

// Round 4
// 70.717 us; speedup vs baseline: 1.4651x; 1.0863x over previous
//
#include <hip/hip_runtime.h>

// GNN_51539607552576 — round 4.
// Phase 1 (proj): [65536 x 256] x [256 x 28] -> d_ws. float4 pixels,
//   8-deep explicit prefetch pipeline, 4 channel-slices, LDS reduce (stride 65).
// Phase 2 (gnn_node): graph math split by output node (grid.y=9) for 9x waves.

namespace {
constexpr int S     = 128 * 128;
constexpr int BATCH = 4;
constexpr int HID   = 10;
constexpr int INDIM = 256;
constexpr int NPIX  = BATCH * S;   // 65536

struct Ptrs {
  const float* __restrict__ xp;
  const float* __restrict__ xh;
  const float* __restrict__ xf;
  const float* __restrict__ p_fea;
  const float* __restrict__ h_fea;
  const float* __restrict__ Wf_comp;  const float* __restrict__ bf_comp;
  const float* __restrict__ Wf_uatt;  const float* __restrict__ bf_uatt;
  const float* __restrict__ Wf_uupd;
  const float* __restrict__ Wh_pdp_f; const float* __restrict__ Wh_pdp_x;
  const float* __restrict__ bh_pdp;
  const float* __restrict__ Wh_att;   const float* __restrict__ bh_att;
  const float* __restrict__ Wh_cu;    const float* __restrict__ bh_cu;
  const float* __restrict__ Wh_cl;    const float* __restrict__ bh_cl;
  const float* __restrict__ Wh_dec_f; const float* __restrict__ Wh_dec_x;
  const float* __restrict__ bh_dec;
  const float* __restrict__ Wh_uatt;  const float* __restrict__ bh_uatt;
  const float* __restrict__ Wh_uupd;
  const float* __restrict__ Wp_pdp_f; const float* __restrict__ Wp_pdp_x;
  const float* __restrict__ bp_pdp;
  const float* __restrict__ Wp_att;   const float* __restrict__ bp_att;
  const float* __restrict__ Wp_dec_f; const float* __restrict__ Wp_dec_x;
  const float* __restrict__ bp_dec;
  const float* __restrict__ Wp_uatt;  const float* __restrict__ bp_uatt;
  const float* __restrict__ Wp_uupd;
  float* __restrict__ out;
  float* __restrict__ ws;
};

__device__ __forceinline__ float sigmoidf(float x) {
  return 1.0f / (1.0f + __expf(-x));
}

// ============================ Phase 1: projections ============================
// ws rows: 0..9 fh, 10..11 hdec, 12..21 fpj, 22..27 pdec. Column = pixel id.
// Block: 256 thr = 64 px-groups (x4 px, float4) x 4 slices (64 ch).
// Per block: 256 pixels. Grid: (NPIX/256, 2 streams) = 512 blocks = 2/CU.

constexpr int LROW = 65;   // LDS row stride (floats); 65 mod 32 = 1 -> conflict-free

template <int NO>  // 12 (h stream) or 16 (p stream)
__device__ __forceinline__ void proj_impl(
    float* lds,                           // [256][LROW]
    const float* __restrict__ fea,
    const float* __restrict__ Wa,         // [10][INDIM]
    const float* __restrict__ Wb,         // [NO-10][INDIM]
    float* __restrict__ ws, int obase) {
  const int t   = threadIdx.x;
  const int pxg = t & 63;
  const int sl  = __builtin_amdgcn_readfirstlane(t >> 6);  // wave-uniform slice
  const int pb  = blockIdx.x * 256;        // block pixel base
  const int b   = pb >> 14;
  const int p0  = pb & (S - 1);

  float4 acc[NO];
#pragma unroll
  for (int o = 0; o < NO; ++o) acc[o] = float4{0.f, 0.f, 0.f, 0.f};

  const float4* __restrict__ base =
      (const float4*)(fea + (size_t)(b * INDIM + sl * 64) * S + p0) + pxg;

  // 8-deep prefetch pipeline over 64 channels (8 batches of 8)
  float4 cur[8];
#pragma unroll
  for (int i = 0; i < 8; ++i) cur[i] = base[(size_t)i * (S / 4)];

#pragma unroll
  for (int blk = 0; blk < 8; ++blk) {
    float4 nxt[8];
    if (blk < 7) {
#pragma unroll
      for (int i = 0; i < 8; ++i)
        nxt[i] = base[(size_t)((blk + 1) * 8 + i) * (S / 4)];
    }
#pragma unroll
    for (int i = 0; i < 8; ++i) {
      const int c = sl * 64 + blk * 8 + i;
      const float4 v = cur[i];
#pragma unroll
      for (int o = 0; o < 10; ++o) {
        const float w = Wa[o * INDIM + c];
        acc[o].x = fmaf(v.x, w, acc[o].x);
        acc[o].y = fmaf(v.y, w, acc[o].y);
        acc[o].z = fmaf(v.z, w, acc[o].z);
        acc[o].w = fmaf(v.w, w, acc[o].w);
      }
#pragma unroll
      for (int o = 10; o < NO; ++o) {
        const float w = Wb[(o - 10) * INDIM + c];
        acc[o].x = fmaf(v.x, w, acc[o].x);
        acc[o].y = fmaf(v.y, w, acc[o].y);
        acc[o].z = fmaf(v.z, w, acc[o].z);
        acc[o].w = fmaf(v.w, w, acc[o].w);
      }
    }
    if (blk < 7) {
#pragma unroll
      for (int i = 0; i < 8; ++i) cur[i] = nxt[i];
    }
  }

  // stage partials: row = sl*64 + pxg, scalar writes (stride-65 rows, no conflicts)
  float* row = lds + (sl * 64 + pxg) * LROW;
#pragma unroll
  for (int o = 0; o < NO; ++o) {
    row[4 * o + 0] = acc[o].x;
    row[4 * o + 1] = acc[o].y;
    row[4 * o + 2] = acc[o].z;
    row[4 * o + 3] = acc[o].w;
  }
  __syncthreads();

  // reduce 4 slices: 256 thr = 64 pxg x 4 output-groups of K outputs
  constexpr int K = NO / 4;
  const int og = t >> 6;
#pragma unroll
  for (int k = 0; k < K; ++k) {
    const int o = og * K + k;
    float r[4] = {0.f, 0.f, 0.f, 0.f};
#pragma unroll
    for (int s2 = 0; s2 < 4; ++s2) {
      const float* rr = lds + (s2 * 64 + pxg) * LROW + 4 * o;
#pragma unroll
      for (int j = 0; j < 4; ++j) r[j] += rr[j];
    }
    float4 res; res.x = r[0]; res.y = r[1]; res.z = r[2]; res.w = r[3];
    *(float4*)(ws + (size_t)(obase + o) * NPIX + pb + pxg * 4) = res;
  }
}

__global__ __launch_bounds__(256, 2) void proj_kernel(Ptrs P) {
  __shared__ float lds[256 * LROW];   // 66.6 KB -> 2 blocks/CU
  if (blockIdx.y == 0) {
    proj_impl<12>(lds, P.h_fea, P.Wh_pdp_f, P.Wh_dec_f, P.ws, 0);
  } else {
    proj_impl<16>(lds, P.p_fea, P.Wp_pdp_f, P.Wp_dec_f, P.ws, 12);
  }
}

// ============================ Phase 2: per-node graph math ============================

__device__ __forceinline__ void att_update_store(
    const float* x, const float* m,
    const float* __restrict__ Wa, float ba, const float* __restrict__ Wu,
    float* __restrict__ outp) {
  float a = ba;
#pragma unroll
  for (int c = 0; c < HID; ++c) a = fmaf(x[c], Wa[c], a);
#pragma unroll
  for (int c = 0; c < HID; ++c) a = fmaf(m[c], Wa[HID + c], a);
  a = sigmoidf(a);
#pragma unroll
  for (int o = 0; o < HID; ++o) {
    float u = 0.f;
#pragma unroll
    for (int c = 0; c < HID; ++c) u = fmaf(x[c], Wu[o * 2 * HID + c], u);
#pragma unroll
    for (int c = 0; c < HID; ++c) u = fmaf(m[c], Wu[o * 2 * HID + HID + c], u);
    u = fmaxf(u, 0.f);
    outp[(size_t)o * S] = x[o] * (1.f - a) + u * a;
  }
}

__device__ __forceinline__ void load10(float* dst, const float* __restrict__ src,
                                       int plane, int p) {
#pragma unroll
  for (int c = 0; c < HID; ++c)
    dst[c] = src[((size_t)plane * HID + c) * S + p];
}

// grid.y = node id: 0..5 parts, 6..7 halves, 8 full
__global__ __launch_bounds__(256) void gnn_node(Ptrs P) {
  const int tid = blockIdx.x * blockDim.x + threadIdx.x;
  const int b = tid >> 14;
  const int p = tid & (S - 1);
  const int y = blockIdx.y;

  if (y == 8) {
    // ---------------- full graph ----------------
    float xh0[HID], xh1[HID], xfv[HID];
    load10(xh0, P.xh, 0 * BATCH + b, p);
    load10(xh1, P.xh, 1 * BATCH + b, p);
    load10(xfv, P.xf, b, p);
    float a0 = P.bf_comp[0], a1 = P.bf_comp[1];
#pragma unroll
    for (int c = 0; c < HID; ++c) {
      a0 = fmaf(xh0[c], P.Wf_comp[c], a0);
      a1 = fmaf(xh1[c], P.Wf_comp[HID + c], a1);
    }
    a0 = sigmoidf(a0); a1 = sigmoidf(a1);
    float msg[HID];
#pragma unroll
    for (int c = 0; c < HID; ++c) msg[c] = a0 * xh0[c] + a1 * xh1[c];
    att_update_store(xfv, msg, P.Wf_uatt, P.bf_uatt[0], P.Wf_uupd,
                     P.out + ((size_t)(8 * BATCH + b) * HID) * S + p);
  } else if (y >= 6) {
    // ---------------- half graph, node h ----------------
    const int h = y - 6;
    float xh_self[HID], xh_oth[HID], xfv[HID], fh[HID];
    load10(xh_self, P.xh, h * BATCH + b, p);
    load10(xh_oth,  P.xh, (1 - h) * BATCH + b, p);
    load10(xfv, P.xf, b, p);
#pragma unroll
    for (int o = 0; o < HID; ++o) fh[o] = P.ws[(size_t)o * NPIX + tid];
    const float hdec = P.ws[(size_t)(10 + h) * NPIX + tid];

    // composition from parts (h=0: parts 0..3 with Wh_cu; h=1: parts 4..5 with Wh_cl)
    const int nsrc = h ? 2 : 4;
    const int sbase = h ? 4 : 0;
    const float* __restrict__ Wc = h ? P.Wh_cl : P.Wh_cu;
    const float* __restrict__ bc = h ? P.bh_cl : P.bh_cu;
    float comp[HID];
#pragma unroll
    for (int o = 0; o < HID; ++o) comp[o] = 0.f;
#pragma unroll
    for (int i = 0; i < 4; ++i) {
      if (i < nsrc) {
        float xpi[HID];
        load10(xpi, P.xp, (sbase + i) * BATCH + b, p);
        float s = bc[i];
#pragma unroll
        for (int c = 0; c < HID; ++c) s = fmaf(xpi[c], Wc[i * HID + c], s);
        s = sigmoidf(s);
#pragma unroll
        for (int c = 0; c < HID; ++c) comp[c] = fmaf(s, xpi[c], comp[c]);
      }
    }

    // attention gates
    float a_self = P.bh_att[h], a_oth = P.bh_att[1 - h];
#pragma unroll
    for (int c = 0; c < HID; ++c) {
      a_self = fmaf(xh_self[c], P.Wh_att[h * HID + c], a_self);
      a_oth  = fmaf(xh_oth[c],  P.Wh_att[(1 - h) * HID + c], a_oth);
    }
    a_self = sigmoidf(a_self); a_oth = sigmoidf(a_oth);
    const float wg = a_oth * (1.f - a_self);

    // decomposition gate (full -> this half)
    float d = hdec + P.bh_dec[h];
#pragma unroll
    for (int c = 0; c < HID; ++c) d = fmaf(xh_self[c], P.Wh_dec_x[h * HID + c], d);
    d = sigmoidf(d);

    // dp from OTHER half + message
    float m[HID];
#pragma unroll
    for (int o = 0; o < HID; ++o) {
      float dp = fh[o] + P.bh_pdp[o];
#pragma unroll
      for (int c = 0; c < HID; ++c) dp = fmaf(xh_oth[c], P.Wh_pdp_x[o * HID + c], dp);
      dp = fmaxf(dp, 0.f);
      m[o] = comp[o] + dp * wg + d * xfv[o];
    }
    att_update_store(xh_self, m, P.Wh_uatt + h * 2 * HID, P.bh_uatt[h],
                     P.Wh_uupd + h * HID * 2 * HID,
                     P.out + ((size_t)((6 + h) * BATCH + b) * HID) * S + p);
  } else {
    // ---------------- part graph, node n ----------------
    const int n = y;
    const int half = (n < 4) ? 0 : 1;
    // source masks per dst (ADJ columns): dst0{1} dst1{0,2,3,4,5} dst2{1} dst3{1} dst4{1,5} dst5{1,4}
    const unsigned masks[6] = {0x02u, 0x3Du, 0x02u, 0x02u, 0x22u, 0x12u};
    const unsigned mask = masks[n];

    float xpn[HID], xh_s[HID], fpj[HID];
    load10(xpn, P.xp, n * BATCH + b, p);
    load10(xh_s, P.xh, half * BATCH + b, p);
#pragma unroll
    for (int o = 0; o < HID; ++o) fpj[o] = P.ws[(size_t)(12 + o) * NPIX + tid];
    const float pdecn = P.ws[(size_t)(22 + n) * NPIX + tid];

    // self attention gate
    float pattn = P.bp_att[n];
#pragma unroll
    for (int c = 0; c < HID; ++c) pattn = fmaf(xpn[c], P.Wp_att[n * HID + c], pattn);
    pattn = sigmoidf(pattn);

    // sum of gated source messages
    float msum[HID];
#pragma unroll
    for (int o = 0; o < HID; ++o) msum[o] = 0.f;
#pragma unroll
    for (int src = 0; src < 6; ++src) {
      if (mask & (1u << src)) {
        float xps[HID];
        load10(xps, P.xp, src * BATCH + b, p);
        float ps = P.bp_att[src];
#pragma unroll
        for (int c = 0; c < HID; ++c) ps = fmaf(xps[c], P.Wp_att[src * HID + c], ps);
        ps = sigmoidf(ps);
#pragma unroll
        for (int o = 0; o < HID; ++o) {
          float dp = fpj[o] + P.bp_pdp[o];
#pragma unroll
          for (int c = 0; c < HID; ++c) dp = fmaf(xps[c], P.Wp_pdp_x[o * HID + c], dp);
          msum[o] = fmaf(fmaxf(dp, 0.f), ps, msum[o]);
        }
      }
    }

    // decomposition gate (half -> part)
    float dg = pdecn + P.bp_dec[n];
#pragma unroll
    for (int c = 0; c < HID; ++c) dg = fmaf(xpn[c], P.Wp_dec_x[n * HID + c], dg);
    dg = sigmoidf(dg);

    const float onem = 1.f - pattn;
    float m[HID];
#pragma unroll
    for (int o = 0; o < HID; ++o) m[o] = onem * msum[o] + dg * xh_s[o];

    att_update_store(xpn, m, P.Wp_uatt + n * 2 * HID, P.bp_uatt[n],
                     P.Wp_uupd + n * HID * 2 * HID,
                     P.out + ((size_t)(n * BATCH + b) * HID) * S + p);
  }
}

}  // namespace

extern "C" void kernel_launch(void* const* d_in, const int* in_sizes, int n_in,
                              void* d_out, int out_size, void* d_ws, size_t ws_size,
                              hipStream_t stream) {
  Ptrs P;
  P.xp       = (const float*)d_in[0];
  P.xh       = (const float*)d_in[1];
  P.xf       = (const float*)d_in[2];
  // d_in[3] = bg_node (unused)
  P.p_fea    = (const float*)d_in[4];
  P.h_fea    = (const float*)d_in[5];
  // d_in[6] = f_fea (unused)
  P.Wf_comp  = (const float*)d_in[7];
  P.bf_comp  = (const float*)d_in[8];
  P.Wf_uatt  = (const float*)d_in[9];
  P.bf_uatt  = (const float*)d_in[10];
  P.Wf_uupd  = (const float*)d_in[11];
  P.Wh_pdp_f = (const float*)d_in[12];
  P.Wh_pdp_x = (const float*)d_in[13];
  P.bh_pdp   = (const float*)d_in[14];
  P.Wh_att   = (const float*)d_in[15];
  P.bh_att   = (const float*)d_in[16];
  P.Wh_cu    = (const float*)d_in[17];
  P.bh_cu    = (const float*)d_in[18];
  P.Wh_cl    = (const float*)d_in[19];
  P.bh_cl    = (const float*)d_in[20];
  P.Wh_dec_f = (const float*)d_in[21];
  P.Wh_dec_x = (const float*)d_in[22];
  P.bh_dec   = (const float*)d_in[23];
  P.Wh_uatt  = (const float*)d_in[24];
  P.bh_uatt  = (const float*)d_in[25];
  P.Wh_uupd  = (const float*)d_in[26];
  P.Wp_pdp_f = (const float*)d_in[27];
  P.Wp_pdp_x = (const float*)d_in[28];
  P.bp_pdp   = (const float*)d_in[29];
  P.Wp_att   = (const float*)d_in[30];
  P.bp_att   = (const float*)d_in[31];
  P.Wp_dec_f = (const float*)d_in[32];
  P.Wp_dec_x = (const float*)d_in[33];
  P.bp_dec   = (const float*)d_in[34];
  P.Wp_uatt  = (const float*)d_in[35];
  P.bp_uatt  = (const float*)d_in[36];
  P.Wp_uupd  = (const float*)d_in[37];
  P.out      = (float*)d_out;
  P.ws       = (float*)d_ws;   // 28 * 65536 * 4 = 7.34 MB

  // Phase 1: 256 pixel-blocks x 2 streams, 256 px per block
  proj_kernel<<<dim3(NPIX / 256, 2), dim3(256), 0, stream>>>(P);
  // Phase 2: 256 pixel-blocks x 9 output nodes
  gnn_node<<<dim3(NPIX / 256, 9), dim3(256), 0, stream>>>(P);
}